// Round 1
// baseline (913.632 us; speedup 1.0000x reference)
//
#include <hip/hip_runtime.h>
#include <cstdint>
#include <cstddef>

#define DEVI __device__ __forceinline__

typedef short bf16x8 __attribute__((ext_vector_type(8)));
typedef float f32x4  __attribute__((ext_vector_type(4)));

constexpr int H_  = 2048;
constexpr int NH  = 16;
constexpr int NKV = 4;
constexpr int HD  = 128;
constexpr int B_  = 4;
constexpr int QL  = 1024;
constexpr int CL  = 3072;
constexpr int KL  = 4096;   // CL + QL
constexpr float EPS = 1e-6f;
// SCALE = HD^-0.5 ; folded with log2(e) so softmax runs in exp2 domain
constexpr float SCALE_LOG2E = 0.08838834764831845f * 1.4426950408889634f;

DEVI unsigned short f2bf(float x) {
  unsigned int u = __float_as_uint(x);
  u += 0x7FFFu + ((u >> 16) & 1u);   // round-to-nearest-even
  return (unsigned short)(u >> 16);
}
DEVI float bf2f(unsigned short u) {
  return __uint_as_float(((unsigned int)u) << 16);
}

// ---------------------------------------------------------------------------
// Weight transpose + fp32 -> bf16 convert:  in (K x N) fp32  ->  out (N x K) bf16
// 64x64 tiles, LDS pad 65 for conflict-free column reads.
// ---------------------------------------------------------------------------
__global__ __launch_bounds__(256)
void wtrans(const float* __restrict__ in, unsigned short* __restrict__ out,
            int K, int N) {
  __shared__ float t[64][65];
  const int ktiles = K >> 6;
  const int kt = blockIdx.x % ktiles;
  const int nt = blockIdx.x / ktiles;
  {
    const int r = threadIdx.x >> 2, cs = threadIdx.x & 3;
    const float4* src = (const float4*)(in + (size_t)(kt * 64 + r) * N + nt * 64 + cs * 16);
    #pragma unroll
    for (int i = 0; i < 4; ++i) {
      float4 v = src[i];
      t[r][cs * 16 + i * 4 + 0] = v.x;
      t[r][cs * 16 + i * 4 + 1] = v.y;
      t[r][cs * 16 + i * 4 + 2] = v.z;
      t[r][cs * 16 + i * 4 + 3] = v.w;
    }
  }
  __syncthreads();
  {
    const int n = threadIdx.x >> 2, ks = threadIdx.x & 3;
    bf16x8 o0, o1;
    #pragma unroll
    for (int i = 0; i < 8; ++i) o0[i] = (short)f2bf(t[ks * 16 + i][n]);
    #pragma unroll
    for (int i = 0; i < 8; ++i) o1[i] = (short)f2bf(t[ks * 16 + 8 + i][n]);
    unsigned short* op = out + (size_t)(nt * 64 + n) * K + kt * 64 + ks * 16;
    *(bf16x8*)(op) = o0;
    *(bf16x8*)(op + 8) = o1;
  }
}

// ---------------------------------------------------------------------------
// Fused GEMM.  C(M x N) = A(M x 2048) @ B(2048 x N), B given transposed bf16.
// MODE 0: Q proj  (A = noise fp32)            -> rmsnorm+rope -> q  (b,h,q,d) bf16
// MODE 1: K proj  (A = concat(ctx,noise))     -> rmsnorm+rope -> k  (b,kv,p,d) bf16
// MODE 2: V proj  (A = concat(ctx,noise))     -> transpose    -> vT (b,kv,d,p) bf16
// MODE 3: O proj  (A = attn_out bf16)         -> fp32 d_out
// 128x128 tile, BK=64, 256 threads, 4 waves in 2x2, 16x16x32 bf16 MFMA.
// ---------------------------------------------------------------------------
struct SmemGemm {
  union {
    struct { unsigned short a[128][72]; unsigned short b[128][72]; } st; // 36864 B
    unsigned short ct[128][138];                                         // 35328 B
  };
};

template <int MODE>
__global__ __launch_bounds__(256)
void gemm_fused(const float* __restrict__ A0,   // noise
                const float* __restrict__ A1,   // ctx
                const unsigned short* __restrict__ Abf,
                const unsigned short* __restrict__ Bt,
                const float* __restrict__ normw,
                const float* __restrict__ cosb, const float* __restrict__ sinb,
                unsigned short* __restrict__ outb, float* __restrict__ outf) {
  constexpr int M  = (MODE == 1 || MODE == 2) ? (B_ * KL) : (B_ * QL);
  constexpr int K  = H_;
  constexpr int MT = M / 128;

  __shared__ SmemGemm sm;
  const int tid  = threadIdx.x;
  const int tm   = blockIdx.x % MT;
  const int tn   = blockIdx.x / MT;
  const int wid  = tid >> 6, lane = tid & 63, quad = lane >> 4, lm = lane & 15;
  const int wm   = wid >> 1, wn = wid & 1;

  f32x4 acc[4][4];
  #pragma unroll
  for (int i = 0; i < 4; ++i)
    #pragma unroll
    for (int j = 0; j < 4; ++j)
      #pragma unroll
      for (int r = 0; r < 4; ++r) acc[i][j][r] = 0.f;

  const int r   = tid >> 1;
  const int seg = tid & 1;
  const int gm  = tm * 128 + r;

  const float* asrc_f = nullptr;
  const unsigned short* asrc_b = nullptr;
  if constexpr (MODE == 0) {
    asrc_f = A0 + (size_t)gm * K;                 // noise rows == (b*QL+q)
  } else if constexpr (MODE == 1 || MODE == 2) {
    const int b = gm >> 12, pos = gm & 4095;      // KL = 4096 rows per batch
    asrc_f = (pos < CL) ? (A1 + ((size_t)(b * CL + pos)) * K)
                        : (A0 + ((size_t)(b * QL + (pos - CL))) * K);
  } else {
    asrc_b = Abf + (size_t)gm * K;
  }
  const unsigned short* bsrc = Bt + (size_t)(tn * 128 + r) * K;

  for (int kt = 0; kt < K / 64; ++kt) {
    __syncthreads();
    // ---- stage A (128 x 64) ----
    if constexpr (MODE == 3) {
      const int4* s = (const int4*)(asrc_b + kt * 64 + seg * 32);
      int4* d = (int4*)&sm.st.a[r][seg * 32];
      d[0] = s[0]; d[1] = s[1]; d[2] = s[2]; d[3] = s[3];
    } else {
      const float4* s = (const float4*)(asrc_f + kt * 64 + seg * 32);
      #pragma unroll
      for (int i = 0; i < 4; ++i) {
        float4 x = s[2 * i], y = s[2 * i + 1];
        bf16x8 v;
        v[0] = (short)f2bf(x.x); v[1] = (short)f2bf(x.y);
        v[2] = (short)f2bf(x.z); v[3] = (short)f2bf(x.w);
        v[4] = (short)f2bf(y.x); v[5] = (short)f2bf(y.y);
        v[6] = (short)f2bf(y.z); v[7] = (short)f2bf(y.w);
        *(bf16x8*)&sm.st.a[r][seg * 32 + i * 8] = v;
      }
    }
    // ---- stage B (128 x 64) ----
    {
      const int4* s = (const int4*)(bsrc + kt * 64 + seg * 32);
      int4* d = (int4*)&sm.st.b[r][seg * 32];
      d[0] = s[0]; d[1] = s[1]; d[2] = s[2]; d[3] = s[3];
    }
    __syncthreads();
    #pragma unroll
    for (int ks = 0; ks < 2; ++ks) {
      bf16x8 af[4], bfr[4];
      #pragma unroll
      for (int i = 0; i < 4; ++i)
        af[i] = *(const bf16x8*)&sm.st.a[wm * 64 + i * 16 + lm][ks * 32 + quad * 8];
      #pragma unroll
      for (int j = 0; j < 4; ++j)
        bfr[j] = *(const bf16x8*)&sm.st.b[wn * 64 + j * 16 + lm][ks * 32 + quad * 8];
      #pragma unroll
      for (int i = 0; i < 4; ++i)
        #pragma unroll
        for (int j = 0; j < 4; ++j)
          acc[i][j] = __builtin_amdgcn_mfma_f32_16x16x32_bf16(af[i], bfr[j], acc[i][j], 0, 0, 0);
    }
  }

  if constexpr (MODE == 3) {
    #pragma unroll
    for (int i = 0; i < 4; ++i)
      #pragma unroll
      for (int j = 0; j < 4; ++j) {
        const int row = tm * 128 + wm * 64 + i * 16 + quad * 4;
        const int col = tn * 128 + wn * 64 + j * 16 + lm;
        #pragma unroll
        for (int rr = 0; rr < 4; ++rr)
          outf[(size_t)(row + rr) * H_ + col] = acc[i][j][rr];
      }
    return;
  }

  // dump C tile to LDS as bf16 (stride 138: odd word stride -> spread banks)
  __syncthreads();
  #pragma unroll
  for (int i = 0; i < 4; ++i)
    #pragma unroll
    for (int j = 0; j < 4; ++j)
      #pragma unroll
      for (int rr = 0; rr < 4; ++rr)
        sm.ct[wm * 64 + i * 16 + quad * 4 + rr][wn * 64 + j * 16 + lm] =
            f2bf(acc[i][j][rr]);
  __syncthreads();

  const int row2 = tid >> 1, half = tid & 1;
  if constexpr (MODE == 0 || MODE == 1) {
    const int gmr = tm * 128 + row2;
    int ci; size_t obase;
    if constexpr (MODE == 0) {
      const int b = gmr >> 10, pos = gmr & 1023;
      ci = (b * KL + CL + pos) * HD;
      obase = ((size_t)((b * NH + tn) * QL + pos)) * HD;
    } else {
      const int b = gmr >> 12, pos = gmr & 4095;
      ci = (b * KL + pos) * HD;
      obase = ((size_t)((b * NKV + tn) * KL + pos)) * HD;
    }
    float ss = 0.f;
    for (int d = half * 64; d < half * 64 + 64; ++d) {
      float v = bf2f(sm.ct[row2][d]);
      ss += v * v;
    }
    ss += __shfl_xor(ss, 1);
    const float rinv = rsqrtf(ss * (1.0f / 128.0f) + EPS);
    #pragma unroll
    for (int d8 = 0; d8 < 8; ++d8) {
      bf16x8 v;
      #pragma unroll
      for (int j = 0; j < 8; ++j) {
        const int d = half * 64 + d8 * 8 + j;
        const float x  = bf2f(sm.ct[row2][d])      * rinv * normw[d];
        const float xo = bf2f(sm.ct[row2][d ^ 64]) * rinv * normw[d ^ 64];
        const float rot = (d < 64) ? -xo : xo;
        v[j] = (short)f2bf(x * cosb[ci + d] + rot * sinb[ci + d]);
      }
      *(bf16x8*)(outb + obase + half * 64 + d8 * 8) = v;
    }
  } else {
    // MODE 2: write V^T  (b, kv, d, pos), pos contiguous
    const int d = row2;
    const int b = (tm * 128) >> 12;
    const int posBase = ((tm * 128) & 4095) + half * 64;
    const size_t obase = ((size_t)((b * NKV + tn) * HD + d)) * KL + posBase;
    #pragma unroll
    for (int k8 = 0; k8 < 8; ++k8) {
      bf16x8 v;
      #pragma unroll
      for (int j = 0; j < 8; ++j)
        v[j] = (short)sm.ct[half * 64 + k8 * 8 + j][d];
      *(bf16x8*)(outb + obase + k8 * 8) = v;
    }
  }
}

// ---------------------------------------------------------------------------
// Flash attention.  Block = one (b,h) x 64 Q rows; 4 waves x 16 rows.
// KTILE=64.  Online softmax in exp2 domain.  q/k/vT/ao all bf16.
// ---------------------------------------------------------------------------
__global__ __launch_bounds__(256)
void attn_kernel(const unsigned short* __restrict__ qb,
                 const unsigned short* __restrict__ kb,
                 const unsigned short* __restrict__ vtb,
                 unsigned short* __restrict__ ao) {
  __shared__ unsigned short kl[64][136];   // K tile: 64 kpos x 128 d (+8 pad)
  __shared__ unsigned short vl[128][72];   // V^T tile: 128 d x 64 kpos (+8 pad)
  __shared__ unsigned short pl[4][16][72]; // per-wave P: 16 q x 64 kpos (+8 pad)

  const int tid = threadIdx.x;
  const int wave = tid >> 6, lane = tid & 63, quad = lane >> 4, lm = lane & 15;
  const int qt = blockIdx.x & 15;
  const int bh = blockIdx.x >> 4;
  const int b = bh >> 4, h = bh & 15, kvh = h >> 2;

  const unsigned short* qptr =
      qb + ((size_t)((b * NH + h) * QL + qt * 64 + wave * 16 + lm)) * HD;
  bf16x8 qf[4];
  #pragma unroll
  for (int kq = 0; kq < 4; ++kq)
    qf[kq] = *(const bf16x8*)(qptr + kq * 32 + quad * 8);

  float mi[4], li[4];
  f32x4 o[8];
  #pragma unroll
  for (int rr = 0; rr < 4; ++rr) { mi[rr] = -1e30f; li[rr] = 0.f; }
  #pragma unroll
  for (int dt = 0; dt < 8; ++dt)
    #pragma unroll
    for (int rr = 0; rr < 4; ++rr) o[dt][rr] = 0.f;

  const unsigned short* kbase = kb + ((size_t)(b * NKV + kvh)) * KL * HD;
  const unsigned short* vbase = vtb + ((size_t)(b * NKV + kvh)) * HD * KL;
  const int kr = tid >> 2, kseg = tid & 3;
  const int vr = tid >> 1, vseg = tid & 1;

  for (int kt = 0; kt < KL / 64; ++kt) {
    __syncthreads();
    {
      const int4* s = (const int4*)(kbase + ((size_t)(kt * 64 + kr)) * HD + kseg * 32);
      int4* d = (int4*)&kl[kr][kseg * 32];
      d[0] = s[0]; d[1] = s[1]; d[2] = s[2]; d[3] = s[3];
    }
    {
      const int4* s = (const int4*)(vbase + (size_t)vr * KL + kt * 64 + vseg * 32);
      int4* d = (int4*)&vl[vr][vseg * 32];
      d[0] = s[0]; d[1] = s[1]; d[2] = s[2]; d[3] = s[3];
    }
    __syncthreads();

    // S = Q K^T  (16 q x 64 kpos per wave)
    f32x4 s4[4];
    #pragma unroll
    for (int nt = 0; nt < 4; ++nt)
      #pragma unroll
      for (int rr = 0; rr < 4; ++rr) s4[nt][rr] = 0.f;
    #pragma unroll
    for (int nt = 0; nt < 4; ++nt)
      #pragma unroll
      for (int kq = 0; kq < 4; ++kq) {
        bf16x8 kf = *(const bf16x8*)&kl[nt * 16 + lm][kq * 32 + quad * 8];
        s4[nt] = __builtin_amdgcn_mfma_f32_16x16x32_bf16(qf[kq], kf, s4[nt], 0, 0, 0);
      }

    // online softmax (exp2 domain)
    float mn[4], al[4], rs[4];
    #pragma unroll
    for (int rr = 0; rr < 4; ++rr) {
      float a0 = s4[0][rr] * SCALE_LOG2E; s4[0][rr] = a0;
      float a1 = s4[1][rr] * SCALE_LOG2E; s4[1][rr] = a1;
      float a2 = s4[2][rr] * SCALE_LOG2E; s4[2][rr] = a2;
      float a3 = s4[3][rr] * SCALE_LOG2E; s4[3][rr] = a3;
      float mx = fmaxf(fmaxf(a0, a1), fmaxf(a2, a3));
      mx = fmaxf(mx, __shfl_xor(mx, 1));
      mx = fmaxf(mx, __shfl_xor(mx, 2));
      mx = fmaxf(mx, __shfl_xor(mx, 4));
      mx = fmaxf(mx, __shfl_xor(mx, 8));
      mn[rr] = fmaxf(mi[rr], mx);
      al[rr] = exp2f(mi[rr] - mn[rr]);
      rs[rr] = 0.f;
    }
    #pragma unroll
    for (int nt = 0; nt < 4; ++nt)
      #pragma unroll
      for (int rr = 0; rr < 4; ++rr) {
        float p = exp2f(s4[nt][rr] - mn[rr]);
        rs[rr] += p;
        pl[wave][quad * 4 + rr][nt * 16 + lm] = f2bf(p);
      }
    #pragma unroll
    for (int rr = 0; rr < 4; ++rr) {
      float v = rs[rr];
      v += __shfl_xor(v, 1);
      v += __shfl_xor(v, 2);
      v += __shfl_xor(v, 4);
      v += __shfl_xor(v, 8);
      li[rr] = li[rr] * al[rr] + v;
      mi[rr] = mn[rr];
    }
    #pragma unroll
    for (int dt = 0; dt < 8; ++dt)
      #pragma unroll
      for (int rr = 0; rr < 4; ++rr) o[dt][rr] *= al[rr];

    // ensure pl writes landed (wave-private region; belt-and-braces)
    __builtin_amdgcn_s_waitcnt(0);
    bf16x8 pf0 = *(const bf16x8*)&pl[wave][lm][quad * 8];
    bf16x8 pf1 = *(const bf16x8*)&pl[wave][lm][32 + quad * 8];
    #pragma unroll
    for (int dt = 0; dt < 8; ++dt) {
      bf16x8 vf0 = *(const bf16x8*)&vl[dt * 16 + lm][quad * 8];
      o[dt] = __builtin_amdgcn_mfma_f32_16x16x32_bf16(pf0, vf0, o[dt], 0, 0, 0);
      bf16x8 vf1 = *(const bf16x8*)&vl[dt * 16 + lm][32 + quad * 8];
      o[dt] = __builtin_amdgcn_mfma_f32_16x16x32_bf16(pf1, vf1, o[dt], 0, 0, 0);
    }
  }

  float inv[4];
  #pragma unroll
  for (int rr = 0; rr < 4; ++rr) inv[rr] = 1.0f / li[rr];
  const int qrow0 = qt * 64 + wave * 16 + quad * 4;
  #pragma unroll
  for (int dt = 0; dt < 8; ++dt)
    #pragma unroll
    for (int rr = 0; rr < 4; ++rr) {
      const size_t idx =
          ((size_t)(b * QL + qrow0 + rr)) * (NH * HD) + h * HD + dt * 16 + lm;
      ao[idx] = f2bf(o[dt][rr] * inv[rr]);
    }
}

// ---------------------------------------------------------------------------
extern "C" void kernel_launch(void* const* d_in, const int* in_sizes, int n_in,
                              void* d_out, int out_size, void* d_ws, size_t ws_size,
                              hipStream_t stream) {
  const float* noise = (const float*)d_in[0];
  const float* ctx   = (const float*)d_in[1];
  const float* cosb  = (const float*)d_in[2];
  const float* sinb  = (const float*)d_in[3];
  const float* Wq    = (const float*)d_in[4];
  const float* Wk    = (const float*)d_in[5];
  const float* Wv    = (const float*)d_in[6];
  const float* Wo    = (const float*)d_in[7];
  const float* qn    = (const float*)d_in[8];
  const float* kn    = (const float*)d_in[9];
  float* out = (float*)d_out;

  char* ws = (char*)d_ws;
  unsigned short* WqT  = (unsigned short*)(ws);                 //  8 MB
  unsigned short* WkT  = (unsigned short*)(ws + 8388608);       //  2 MB
  unsigned short* WvT  = (unsigned short*)(ws + 10485760);      //  2 MB
  unsigned short* WoT  = (unsigned short*)(ws + 12582912);      //  8 MB
  unsigned short* qbuf = (unsigned short*)(ws + 20971520);      // 16 MB
  unsigned short* kbuf = (unsigned short*)(ws + 37748736);      // 16 MB
  unsigned short* vtb  = (unsigned short*)(ws + 54525952);      // 16 MB
  unsigned short* aob  = (unsigned short*)(ws + 71303168);      // 16 MB  (total 84 MB)

  wtrans<<<dim3(1024), dim3(256), 0, stream>>>(Wq, WqT, 2048, 2048);
  wtrans<<<dim3(256),  dim3(256), 0, stream>>>(Wk, WkT, 2048, 512);
  wtrans<<<dim3(256),  dim3(256), 0, stream>>>(Wv, WvT, 2048, 512);
  wtrans<<<dim3(1024), dim3(256), 0, stream>>>(Wo, WoT, 2048, 2048);

  gemm_fused<0><<<dim3(32 * 16), dim3(256), 0, stream>>>(
      noise, nullptr, nullptr, WqT, qn, cosb, sinb, qbuf, nullptr);
  gemm_fused<1><<<dim3(128 * 4), dim3(256), 0, stream>>>(
      noise, ctx, nullptr, WkT, kn, cosb, sinb, kbuf, nullptr);
  gemm_fused<2><<<dim3(128 * 4), dim3(256), 0, stream>>>(
      noise, ctx, nullptr, WvT, nullptr, nullptr, nullptr, vtb, nullptr);

  attn_kernel<<<dim3(1024), dim3(256), 0, stream>>>(qbuf, kbuf, vtb, aob);

  gemm_fused<3><<<dim3(32 * 16), dim3(256), 0, stream>>>(
      nullptr, nullptr, aob, WoT, nullptr, nullptr, nullptr, nullptr, out);
}

// Round 2
// 617.789 us; speedup vs baseline: 1.4789x; 1.4789x over previous
//
#include <hip/hip_runtime.h>
#include <cstdint>
#include <cstddef>

#define DEVI __device__ __forceinline__

typedef short bf16x8 __attribute__((ext_vector_type(8)));
typedef short bf16x4 __attribute__((ext_vector_type(4)));
typedef float f32x4  __attribute__((ext_vector_type(4)));

constexpr int H_  = 2048;
constexpr int NH  = 16;
constexpr int NKV = 4;
constexpr int HD  = 128;
constexpr int B_  = 4;
constexpr int QL  = 1024;
constexpr int CL  = 3072;
constexpr int KL  = 4096;   // CL + QL
constexpr float EPS = 1e-6f;
// SCALE * log2(e): folded into stored Q so attention softmax is bare exp2
constexpr float SCALE_LOG2E = 0.08838834764831845f * 1.4426950408889634f;

DEVI unsigned short f2bf(float x) {
  unsigned int u = __float_as_uint(x);
  u += 0x7FFFu + ((u >> 16) & 1u);   // RNE
  return (unsigned short)(u >> 16);
}
DEVI float bf2f(unsigned short u) {
  return __uint_as_float(((unsigned int)u) << 16);
}
// pack 4 fp32 -> 4 bf16 with round-half-up (cheap: add + v_perm)
DEVI bf16x4 mk4(float a, float b, float c, float d) {
  unsigned ua = __float_as_uint(a) + 0x8000u, ub = __float_as_uint(b) + 0x8000u;
  unsigned uc = __float_as_uint(c) + 0x8000u, ud = __float_as_uint(d) + 0x8000u;
  union { unsigned u[2]; bf16x4 v; } r;
  r.u[0] = __builtin_amdgcn_perm(ub, ua, 0x07060302u);  // hi16(b):hi16(a)
  r.u[1] = __builtin_amdgcn_perm(ud, uc, 0x07060302u);
  return r.v;
}

DEVI void async16(const void* g, void* l) {
  __builtin_amdgcn_global_load_lds(
      (const __attribute__((address_space(1))) void*)g,
      (__attribute__((address_space(3))) void*)l, 16, 0, 0);
}

// ---------------------------------------------------------------------------
// prep: kvin_bf[b][pos][h] = bf16(concat(ctx, noise))   (b, KL, H)
// ---------------------------------------------------------------------------
__global__ __launch_bounds__(256)
void prep(const float* __restrict__ noise, const float* __restrict__ ctx,
          unsigned short* __restrict__ kvin) {
  const size_t t = (size_t)blockIdx.x * 256 + threadIdx.x;   // one 8-elem chunk
  const size_t e = t * 8;
  const int row = (int)(e / H_), col = (int)(e % H_);
  const int b = row >> 12, pos = row & 4095;
  const float* src = (pos < CL) ? ctx + ((size_t)(b * CL + pos)) * H_ + col
                                : noise + ((size_t)(b * QL + (pos - CL))) * H_ + col;
  float4 x = ((const float4*)src)[0], y = ((const float4*)src)[1];
  bf16x8 v;
  v[0] = (short)f2bf(x.x); v[1] = (short)f2bf(x.y);
  v[2] = (short)f2bf(x.z); v[3] = (short)f2bf(x.w);
  v[4] = (short)f2bf(y.x); v[5] = (short)f2bf(y.y);
  v[6] = (short)f2bf(y.z); v[7] = (short)f2bf(y.w);
  *(bf16x8*)(kvin + e) = v;
}

// ---------------------------------------------------------------------------
// Weight transpose + fp32 -> bf16:  in (K x N) fp32  ->  out (N x K) bf16
// ---------------------------------------------------------------------------
__global__ __launch_bounds__(256)
void wtrans(const float* __restrict__ in, unsigned short* __restrict__ out,
            int K, int N) {
  __shared__ float t[64][65];
  const int ktiles = K >> 6;
  const int kt = blockIdx.x % ktiles;
  const int nt = blockIdx.x / ktiles;
  {
    const int r = threadIdx.x >> 2, cs = threadIdx.x & 3;
    const float4* src = (const float4*)(in + (size_t)(kt * 64 + r) * N + nt * 64 + cs * 16);
    #pragma unroll
    for (int i = 0; i < 4; ++i) {
      float4 v = src[i];
      t[r][cs * 16 + i * 4 + 0] = v.x;
      t[r][cs * 16 + i * 4 + 1] = v.y;
      t[r][cs * 16 + i * 4 + 2] = v.z;
      t[r][cs * 16 + i * 4 + 3] = v.w;
    }
  }
  __syncthreads();
  {
    const int n = threadIdx.x >> 2, ks = threadIdx.x & 3;
    bf16x8 o0, o1;
    #pragma unroll
    for (int i = 0; i < 8; ++i) o0[i] = (short)f2bf(t[ks * 16 + i][n]);
    #pragma unroll
    for (int i = 0; i < 8; ++i) o1[i] = (short)f2bf(t[ks * 16 + 8 + i][n]);
    unsigned short* op = out + (size_t)(nt * 64 + n) * K + kt * 64 + ks * 16;
    *(bf16x8*)(op) = o0;
    *(bf16x8*)(op + 8) = o1;
  }
}

// ---------------------------------------------------------------------------
// m97-style GEMM, both operands bf16 via global_load_lds w/ XOR granule swizzle.
// C(M x N) = A(M x 2048) @ B(2048 x N), B given transposed (N x K) bf16.
// MODE 0: A=kvin rows (b,CL+q)  -> rmsnorm+rope, *SCALE_LOG2E -> q  (b,h,q,d)
// MODE 1: A=kvin                -> rmsnorm+rope -> k  (b,kv,p,d)
// MODE 2: A=kvin                -> transpose    -> vT (b,kv,d,p)
// MODE 3: A=attn_out bf16       -> fp32 d_out
// ---------------------------------------------------------------------------
template <int MODE>
__global__ __launch_bounds__(256)
void gemm2(const unsigned short* __restrict__ Abf,
           const unsigned short* __restrict__ Bt,
           const float* __restrict__ normw,
           const float* __restrict__ cosb, const float* __restrict__ sinb,
           unsigned short* __restrict__ outb, float* __restrict__ outf) {
  constexpr int M  = (MODE == 1 || MODE == 2) ? (B_ * KL) : (B_ * QL);
  constexpr int K  = H_;
  constexpr int MT = M / 128;

  __shared__ union U {
    struct { unsigned short a[128][64]; unsigned short b[128][64]; } st; // 32 KB
    unsigned short ct[128][138];                                         // 35.3 KB
  } sm;

  const int tid  = threadIdx.x;
  const int tm   = blockIdx.x % MT;
  const int tn   = blockIdx.x / MT;
  const int wid  = tid >> 6, lane = tid & 63, quad = lane >> 4, lm = lane & 15;
  const int wm   = wid >> 1, wn = wid & 1;

  f32x4 acc[4][4];
  #pragma unroll
  for (int i = 0; i < 4; ++i)
    #pragma unroll
    for (int j = 0; j < 4; ++j)
      #pragma unroll
      for (int r = 0; r < 4; ++r) acc[i][j][r] = 0.f;

  // staging pointers (per 16B granule; LDS side is linear: offset 16*idx)
  const unsigned short* agp[4];
  const unsigned short* bgp[4];
  #pragma unroll
  for (int i = 0; i < 4; ++i) {
    const int idx = i * 256 + tid;
    const int arow = idx >> 3, g = idx & 7, gg = g ^ (arow & 7);
    int grow;
    if constexpr (MODE == 0) {
      const int gmr = tm * 128 + arow;
      grow = (gmr >> 10) * KL + CL + (gmr & 1023);
    } else {
      grow = tm * 128 + arow;
    }
    agp[i] = Abf + (size_t)grow * K + gg * 8;
    bgp[i] = Bt + (size_t)(tn * 128 + arow) * K + gg * 8;
  }

  for (int kt = 0; kt < K / 64; ++kt) {
    __syncthreads();
    #pragma unroll
    for (int i = 0; i < 4; ++i) {
      async16(agp[i] + kt * 64, (char*)&sm.st.a[0][0] + (i * 256 + wid * 64) * 16);
      async16(bgp[i] + kt * 64, (char*)&sm.st.b[0][0] + (i * 256 + wid * 64) * 16);
    }
    __syncthreads();
    #pragma unroll
    for (int ks = 0; ks < 2; ++ks) {
      bf16x8 af[4], bfr[4];
      #pragma unroll
      for (int i = 0; i < 4; ++i) {
        const int swz = (ks * 4 + quad) ^ (lm & 7);
        af[i] = *(const bf16x8*)&sm.st.a[wm * 64 + i * 16 + lm][swz * 8];
      }
      #pragma unroll
      for (int j = 0; j < 4; ++j) {
        const int swz = (ks * 4 + quad) ^ (lm & 7);
        bfr[j] = *(const bf16x8*)&sm.st.b[wn * 64 + j * 16 + lm][swz * 8];
      }
      #pragma unroll
      for (int i = 0; i < 4; ++i)
        #pragma unroll
        for (int j = 0; j < 4; ++j)
          acc[i][j] = __builtin_amdgcn_mfma_f32_16x16x32_bf16(af[i], bfr[j], acc[i][j], 0, 0, 0);
    }
  }

  if constexpr (MODE == 3) {
    #pragma unroll
    for (int i = 0; i < 4; ++i)
      #pragma unroll
      for (int j = 0; j < 4; ++j) {
        const int row = tm * 128 + wm * 64 + i * 16 + quad * 4;
        const int col = tn * 128 + wn * 64 + j * 16 + lm;
        #pragma unroll
        for (int rr = 0; rr < 4; ++rr)
          outf[(size_t)(row + rr) * H_ + col] = acc[i][j][rr];
      }
    return;
  }

  // C tile -> LDS bf16
  __syncthreads();
  #pragma unroll
  for (int i = 0; i < 4; ++i)
    #pragma unroll
    for (int j = 0; j < 4; ++j)
      #pragma unroll
      for (int rr = 0; rr < 4; ++rr)
        sm.ct[wm * 64 + i * 16 + quad * 4 + rr][wn * 64 + j * 16 + lm] =
            f2bf(acc[i][j][rr]);
  __syncthreads();

  const int row2 = tid >> 1, half = tid & 1;
  if constexpr (MODE == 0 || MODE == 1) {
    const int gmr = tm * 128 + row2;
    int ci; size_t obase;
    if constexpr (MODE == 0) {
      const int b = gmr >> 10, pos = gmr & 1023;
      ci = (b * KL + CL + pos) * HD;
      obase = ((size_t)((b * NH + tn) * QL + pos)) * HD;
    } else {
      const int b = gmr >> 12, pos = gmr & 4095;
      ci = (b * KL + pos) * HD;
      obase = ((size_t)((b * NKV + tn) * KL + pos)) * HD;
    }
    float ss = 0.f;
    for (int d = half * 64; d < half * 64 + 64; ++d) {
      float v = bf2f(sm.ct[row2][d]);
      ss += v * v;
    }
    ss += __shfl_xor(ss, 1);
    const float rinv = rsqrtf(ss * (1.0f / 128.0f) + EPS);
    constexpr float OSC = (MODE == 0) ? SCALE_LOG2E : 1.0f;
    #pragma unroll
    for (int d8 = 0; d8 < 8; ++d8) {
      bf16x8 v;
      #pragma unroll
      for (int j = 0; j < 8; ++j) {
        const int d = half * 64 + d8 * 8 + j;
        const float x  = bf2f(sm.ct[row2][d])      * rinv * normw[d];
        const float xo = bf2f(sm.ct[row2][d ^ 64]) * rinv * normw[d ^ 64];
        const float rot = (d < 64) ? -xo : xo;
        v[j] = (short)f2bf((x * cosb[ci + d] + rot * sinb[ci + d]) * OSC);
      }
      *(bf16x8*)(outb + obase + half * 64 + d8 * 8) = v;
    }
  } else {
    // MODE 2: V^T  (b, kv, d, pos)
    const int d = row2;
    const int b = (tm * 128) >> 12;
    const int posBase = ((tm * 128) & 4095) + half * 64;
    const size_t obase = ((size_t)((b * NKV + tn) * HD + d)) * KL + posBase;
    #pragma unroll
    for (int k8 = 0; k8 < 8; ++k8) {
      bf16x8 v;
      #pragma unroll
      for (int j = 0; j < 8; ++j)
        v[j] = (short)sm.ct[half * 64 + k8 * 8 + j][d];
      *(bf16x8*)(outb + obase + k8 * 8) = v;
    }
  }
}

// ---------------------------------------------------------------------------
// Flash attention v2.  Block = one (b,h) x 128 q rows; 4 waves x 32 q rows.
// S^T = K Q^T (16x16x32) -> p = exp2(s) in regs -> O^T += V^T P^T (16x16x16,
// P^T taken directly from S^T's C-layout registers).  No-max softmax
// (|s|<=16.3 in exp2 domain, bounded by RMSNorm), li reduced once at end.
// K/V tiles staged via global_load_lds with XOR granule swizzle.
// ---------------------------------------------------------------------------
__global__ __launch_bounds__(256)
void attn2(const unsigned short* __restrict__ qb,
           const unsigned short* __restrict__ kb,
           const unsigned short* __restrict__ vtb,
           unsigned short* __restrict__ ao) {
  __shared__ unsigned short kl[64][128];   // 16 KB : K tile (kpos x d), swizzled
  __shared__ unsigned short vl[128][64];   // 16 KB : V^T tile (d x kpos), swizzled

  const int tid = threadIdx.x;
  const int wave = tid >> 6, lane = tid & 63, quad = lane >> 4, lm = lane & 15;
  const int qblk = blockIdx.x & 7;
  const int bh = blockIdx.x >> 3;
  const int b = bh >> 4, h = bh & 15, kvh = h >> 2;
  const int q0 = qblk * 128 + wave * 32;

  // Q fragments (already scaled by SCALE_LOG2E at projection time)
  bf16x8 qf[2][4];
  const unsigned short* qbase = qb + ((size_t)((b * NH + h) * QL + q0)) * HD;
  #pragma unroll
  for (int qt = 0; qt < 2; ++qt)
    #pragma unroll
    for (int kq = 0; kq < 4; ++kq)
      qf[qt][kq] = *(const bf16x8*)(qbase + (qt * 16 + lm) * HD + kq * 32 + quad * 8);

  f32x4 o[2][8];
  float li[2] = {0.f, 0.f};
  #pragma unroll
  for (int qt = 0; qt < 2; ++qt)
    #pragma unroll
    for (int dt = 0; dt < 8; ++dt)
      #pragma unroll
      for (int rr = 0; rr < 4; ++rr) o[qt][dt][rr] = 0.f;

  const unsigned short* kbase = kb + ((size_t)(b * NKV + kvh)) * KL * HD;
  const unsigned short* vbase = vtb + ((size_t)(b * NKV + kvh)) * HD * KL;

  const unsigned short* kgp[4];
  const unsigned short* vgp[4];
  #pragma unroll
  for (int i = 0; i < 4; ++i) {
    const int idx = i * 256 + tid;
    const int krow = idx >> 4, gc = idx & 15;
    const int gg = (gc & 8) | ((gc & 7) ^ (krow & 7));
    kgp[i] = kbase + (size_t)krow * HD + gg * 8;
    const int vrow = idx >> 3, g = idx & 7;
    const int gv = g ^ (vrow & 7);
    vgp[i] = vbase + (size_t)vrow * KL + gv * 8;
  }

  for (int kt = 0; kt < KL / 64; ++kt) {
    __syncthreads();
    #pragma unroll
    for (int i = 0; i < 4; ++i) {
      async16(kgp[i] + (size_t)kt * 64 * HD, (char*)&kl[0][0] + (i * 256 + wave * 64) * 16);
      async16(vgp[i] + kt * 64,              (char*)&vl[0][0] + (i * 256 + wave * 64) * 16);
    }
    __syncthreads();

    #pragma unroll
    for (int nt = 0; nt < 4; ++nt) {
      bf16x8 kf[4];
      #pragma unroll
      for (int kq = 0; kq < 4; ++kq) {
        const int gc = kq * 4 + quad;
        const int swz = (gc & 8) | ((gc & 7) ^ (lm & 7));
        kf[kq] = *(const bf16x8*)&kl[nt * 16 + lm][swz * 8];
      }
      f32x4 s0 = {0.f, 0.f, 0.f, 0.f}, s1 = {0.f, 0.f, 0.f, 0.f};
      #pragma unroll
      for (int kq = 0; kq < 4; ++kq) {
        s0 = __builtin_amdgcn_mfma_f32_16x16x32_bf16(kf[kq], qf[0][kq], s0, 0, 0, 0);
        s1 = __builtin_amdgcn_mfma_f32_16x16x32_bf16(kf[kq], qf[1][kq], s1, 0, 0, 0);
      }
      float e00 = __builtin_amdgcn_exp2f(s0[0]), e01 = __builtin_amdgcn_exp2f(s0[1]);
      float e02 = __builtin_amdgcn_exp2f(s0[2]), e03 = __builtin_amdgcn_exp2f(s0[3]);
      float e10 = __builtin_amdgcn_exp2f(s1[0]), e11 = __builtin_amdgcn_exp2f(s1[1]);
      float e12 = __builtin_amdgcn_exp2f(s1[2]), e13 = __builtin_amdgcn_exp2f(s1[3]);
      li[0] += (e00 + e01) + (e02 + e03);
      li[1] += (e10 + e11) + (e12 + e13);
      bf16x4 p0 = mk4(e00, e01, e02, e03);
      bf16x4 p1 = mk4(e10, e11, e12, e13);
      #pragma unroll
      for (int dt = 0; dt < 8; ++dt) {
        const int gv = (nt * 2 + (quad >> 1)) ^ (lm & 7);
        bf16x4 vf = *(const bf16x4*)&vl[dt * 16 + lm][gv * 8 + (quad & 1) * 4];
        o[0][dt] = __builtin_amdgcn_mfma_f32_16x16x16bf16_1k(vf, p0, o[0][dt], 0, 0, 0);
        o[1][dt] = __builtin_amdgcn_mfma_f32_16x16x16bf16_1k(vf, p1, o[1][dt], 0, 0, 0);
      }
    }
  }

  #pragma unroll
  for (int qt = 0; qt < 2; ++qt) {
    float l = li[qt];
    l += __shfl_xor(l, 16);
    l += __shfl_xor(l, 32);
    const float inv = 1.0f / l;
    const size_t rowbase = ((size_t)(b * QL + q0 + qt * 16 + lm)) * (NH * HD) + h * HD;
    #pragma unroll
    for (int dt = 0; dt < 8; ++dt) {
      bf16x4 v = mk4(o[qt][dt][0] * inv, o[qt][dt][1] * inv,
                     o[qt][dt][2] * inv, o[qt][dt][3] * inv);
      *(bf16x4*)(ao + rowbase + dt * 16 + quad * 4) = v;
    }
  }
}

// ---------------------------------------------------------------------------
extern "C" void kernel_launch(void* const* d_in, const int* in_sizes, int n_in,
                              void* d_out, int out_size, void* d_ws, size_t ws_size,
                              hipStream_t stream) {
  const float* noise = (const float*)d_in[0];
  const float* ctx   = (const float*)d_in[1];
  const float* cosb  = (const float*)d_in[2];
  const float* sinb  = (const float*)d_in[3];
  const float* Wq    = (const float*)d_in[4];
  const float* Wk    = (const float*)d_in[5];
  const float* Wv    = (const float*)d_in[6];
  const float* Wo    = (const float*)d_in[7];
  const float* qn    = (const float*)d_in[8];
  const float* kn    = (const float*)d_in[9];
  float* out = (float*)d_out;

  char* ws = (char*)d_ws;
  // kvin: 64 MB [0,64M).  aob aliases kvin[0:16M) (kvin dead after V-proj).
  unsigned short* kvin = (unsigned short*)(ws);
  unsigned short* aob  = (unsigned short*)(ws);
  unsigned short* WqT  = (unsigned short*)(ws + 67108864);            //  8 MB
  unsigned short* WkT  = (unsigned short*)(ws + 67108864 + 8388608);  //  2 MB
  unsigned short* WvT  = (unsigned short*)(ws + 67108864 + 10485760); //  2 MB
  unsigned short* WoT  = (unsigned short*)(ws + 67108864 + 12582912); //  8 MB
  unsigned short* qbuf = (unsigned short*)(ws + 67108864 + 20971520); // 16 MB
  unsigned short* kbuf = (unsigned short*)(ws + 67108864 + 37748736); // 16 MB
  unsigned short* vtb  = (unsigned short*)(ws + 67108864 + 54525952); // 16 MB (total 132 MB)

  prep<<<dim3((B_ * KL * H_) / 8 / 256), dim3(256), 0, stream>>>(noise, ctx, kvin);

  wtrans<<<dim3(1024), dim3(256), 0, stream>>>(Wq, WqT, 2048, 2048);
  wtrans<<<dim3(256),  dim3(256), 0, stream>>>(Wk, WkT, 2048, 512);
  wtrans<<<dim3(256),  dim3(256), 0, stream>>>(Wv, WvT, 2048, 512);
  wtrans<<<dim3(1024), dim3(256), 0, stream>>>(Wo, WoT, 2048, 2048);

  gemm2<0><<<dim3(32 * 16), dim3(256), 0, stream>>>(
      kvin, WqT, qn, cosb, sinb, qbuf, nullptr);
  gemm2<1><<<dim3(128 * 4), dim3(256), 0, stream>>>(
      kvin, WkT, kn, cosb, sinb, kbuf, nullptr);
  gemm2<2><<<dim3(128 * 4), dim3(256), 0, stream>>>(
      kvin, WvT, nullptr, nullptr, nullptr, vtb, nullptr);

  attn2<<<dim3(512), dim3(256), 0, stream>>>(qbuf, kbuf, vtb, aob);

  gemm2<3><<<dim3(32 * 16), dim3(256), 0, stream>>>(
      aob, WoT, nullptr, nullptr, nullptr, nullptr, out);
}